// Round 1
// baseline (1024.668 us; speedup 1.0000x reference)
//
#include <hip/hip_runtime.h>
#include <hip/hip_bf16.h>
#include <math.h>

// GCN 2-layer: h1 = relu(Agg(x@W1)+b1); out = log_softmax(Agg(h1@W2)+b2)
// Agg uses symmetric norm dinv[row]*dinv[col]; factorized as
//   out[i] = dinv[i] * ( sum_{e: col=i} hs[row_e] + hs[i] ) + b
// where hs[j] = dinv[j] * h[j].

#define GNN_N 100000
#define GNN_E 1600000

__global__ __launch_bounds__(256) void k_init_deg(float* deg, int n) {
    int i = blockIdx.x * 256 + threadIdx.x;
    if (i < n) deg[i] = 1.0f;   // self loop
}

__global__ __launch_bounds__(256) void k_count(const int* __restrict__ col,
                                               float* deg, int e) {
    int i = blockIdx.x * 256 + threadIdx.x;
    if (i < e) atomicAdd(&deg[col[i]], 1.0f);
}

__global__ __launch_bounds__(256) void k_dinv(float* deg, int n) {
    int i = blockIdx.x * 256 + threadIdx.x;
    if (i < n) deg[i] = rsqrtf(deg[i]);   // deg >= 1 always (self loop)
}

// h1s[i,f] = dinv[i] * sum_k x[i,k] * W1[k,f]
// block: 64 nodes; 256 threads = 32 nodegroups(2 nodes) x 8 featgroups(4 feats)
#define MM1_NODES 64
__global__ __launch_bounds__(256) void k_matmul1(const float* __restrict__ x,
                                                 const float* __restrict__ W1,
                                                 const float* __restrict__ dinv,
                                                 float* __restrict__ h1s, int n) {
    __shared__ float xs[MM1_NODES * 129];   // padded stride: bank = (node+k)%32
    __shared__ float w1s[128 * 32];
    const int tid = threadIdx.x;
    const int nodeBase = blockIdx.x * MM1_NODES;

    // stage W1 (4096 floats)
    {
        const float4* w4 = (const float4*)W1;
        float4* s4 = (float4*)w1s;
        for (int i = tid; i < 1024; i += 256) s4[i] = w4[i];
    }
    // stage x tile (64 x 128) into padded LDS
    {
        const float4* x4 = (const float4*)x;
        for (int i = tid; i < MM1_NODES * 32; i += 256) {
            int node = i >> 5;
            int k4 = i & 31;
            float4 v = make_float4(0.f, 0.f, 0.f, 0.f);
            if (nodeBase + node < n)
                v = x4[(size_t)(nodeBase + node) * 32 + k4];
            int b = node * 129 + k4 * 4;
            xs[b + 0] = v.x; xs[b + 1] = v.y; xs[b + 2] = v.z; xs[b + 3] = v.w;
        }
    }
    __syncthreads();

    const int fg = tid & 7;    // feats 4*fg .. 4*fg+3
    const int ng = tid >> 3;   // nodes 2*ng, 2*ng+1
    const int n0 = ng * 2;
    float4 acc0 = make_float4(0.f, 0.f, 0.f, 0.f);
    float4 acc1 = make_float4(0.f, 0.f, 0.f, 0.f);
    const float4* w1s4 = (const float4*)w1s;   // [128][8]
    const float* xr0 = &xs[n0 * 129];
    const float* xr1 = &xs[(n0 + 1) * 129];
    #pragma unroll 8
    for (int k = 0; k < 128; ++k) {
        float4 w = w1s4[k * 8 + fg];
        float a = xr0[k];
        float b = xr1[k];
        acc0.x += a * w.x; acc0.y += a * w.y; acc0.z += a * w.z; acc0.w += a * w.w;
        acc1.x += b * w.x; acc1.y += b * w.y; acc1.z += b * w.z; acc1.w += b * w.w;
    }
    int gn0 = nodeBase + n0;
    if (gn0 < n) {
        float d = dinv[gn0];
        float4 o = make_float4(acc0.x * d, acc0.y * d, acc0.z * d, acc0.w * d);
        ((float4*)h1s)[(size_t)gn0 * 8 + fg] = o;
    }
    if (gn0 + 1 < n) {
        float d = dinv[gn0 + 1];
        float4 o = make_float4(acc1.x * d, acc1.y * d, acc1.z * d, acc1.w * d);
        ((float4*)h1s)[(size_t)(gn0 + 1) * 8 + fg] = o;
    }
}

// 8 threads per edge; float4 gather of h1s row; scalar atomics to agg1
__global__ __launch_bounds__(256) void k_edge_agg1(const int* __restrict__ row,
                                                   const int* __restrict__ col,
                                                   const float* __restrict__ h1s,
                                                   float* agg1, int e) {
    int t = blockIdx.x * 256 + threadIdx.x;
    int ei = t >> 3;
    int j = t & 7;
    if (ei >= e) return;
    int r = row[ei];
    int c = col[ei];
    float4 v = ((const float4*)h1s)[(size_t)r * 8 + j];
    float* dst = agg1 + (size_t)c * 32 + j * 4;
    atomicAdd(dst + 0, v.x);
    atomicAdd(dst + 1, v.y);
    atomicAdd(dst + 2, v.z);
    atomicAdd(dst + 3, v.w);
}

// a1 = relu(dinv*(agg1+h1s)+b1); h2s = dinv * (a1 @ W2)  via 32-lane reduce
__global__ __launch_bounds__(256) void k_finish1(const float* __restrict__ agg1,
                                                 const float* __restrict__ h1s,
                                                 const float* __restrict__ dinv,
                                                 const float* __restrict__ b1,
                                                 const float* __restrict__ W2,
                                                 float* __restrict__ h2s, int n) {
    int tid = threadIdx.x;
    int f = tid & 31;
    int ln = tid >> 5;
    int node = blockIdx.x * 8 + ln;
    float a = 0.f;
    float d = 0.f;
    if (node < n) {
        d = dinv[node];
        size_t idx = (size_t)node * 32 + f;
        float pre = d * (agg1[idx] + h1s[idx]) + b1[f];
        a = fmaxf(pre, 0.f);
    }
    float s0 = a * W2[f * 2 + 0];
    float s1 = a * W2[f * 2 + 1];
    #pragma unroll
    for (int m = 16; m >= 1; m >>= 1) {
        s0 += __shfl_xor(s0, m);
        s1 += __shfl_xor(s1, m);
    }
    if (f == 0 && node < n) {
        ((float2*)h2s)[node] = make_float2(d * s0, d * s1);
    }
}

__global__ __launch_bounds__(256) void k_edge_agg2(const int* __restrict__ row,
                                                   const int* __restrict__ col,
                                                   const float* __restrict__ h2s,
                                                   float* agg2, int e) {
    int i = blockIdx.x * 256 + threadIdx.x;
    if (i >= e) return;
    int r = row[i];
    int c = col[i];
    float2 v = ((const float2*)h2s)[r];
    atomicAdd(&agg2[(size_t)c * 2 + 0], v.x);
    atomicAdd(&agg2[(size_t)c * 2 + 1], v.y);
}

__global__ __launch_bounds__(256) void k_finish2(const float* __restrict__ agg2,
                                                 const float* __restrict__ h2s,
                                                 const float* __restrict__ dinv,
                                                 const float* __restrict__ b2,
                                                 float* __restrict__ out, int n) {
    int i = blockIdx.x * 256 + threadIdx.x;
    if (i >= n) return;
    float d = dinv[i];
    float2 g = ((const float2*)agg2)[i];
    float2 h = ((const float2*)h2s)[i];
    float v0 = d * (g.x + h.x) + b2[0];
    float v1 = d * (g.y + h.y) + b2[1];
    float m = fmaxf(v0, v1);
    float l = m + logf(expf(v0 - m) + expf(v1 - m));
    ((float2*)out)[i] = make_float2(v0 - l, v1 - l);
}

extern "C" void kernel_launch(void* const* d_in, const int* in_sizes, int n_in,
                              void* d_out, int out_size, void* d_ws, size_t ws_size,
                              hipStream_t stream) {
    const float* x  = (const float*)d_in[0];
    const int*   ei = (const int*)d_in[1];   // [2,E] int32 (jax demotes int64)
    const float* W1 = (const float*)d_in[2];
    const float* b1 = (const float*)d_in[3];
    const float* W2 = (const float*)d_in[4];
    const float* b2 = (const float*)d_in[5];
    float* out = (float*)d_out;
    float* ws = (float*)d_ws;

    const int N = GNN_N, E = GNN_E;
    const int* row = ei;
    const int* col = ei + E;

    // workspace layout (floats):
    float* dinv = ws;                    // [0, 100000)   deg -> dinv in place
    float* h1s  = ws + 100000;           // [N*32]
    float* agg1 = ws + 3300000;          // [N*32]
    float* agg2 = ws + 6500000;          // [N*2]
    float* h2s  = ws + 6700000;          // [N*2]  (total 6.9M floats = 27.6 MB)

    // zero agg1+agg2 (contiguous)
    hipMemsetAsync(agg1, 0, (size_t)(3200000 + 200000) * sizeof(float), stream);

    k_init_deg<<<(N + 255) / 256, 256, 0, stream>>>(dinv, N);
    k_count<<<(E + 255) / 256, 256, 0, stream>>>(col, dinv, E);
    k_dinv<<<(N + 255) / 256, 256, 0, stream>>>(dinv, N);
    k_matmul1<<<(N + MM1_NODES - 1) / MM1_NODES, 256, 0, stream>>>(x, W1, dinv, h1s, N);
    k_edge_agg1<<<(E * 8) / 256, 256, 0, stream>>>(row, col, h1s, agg1, E);
    k_finish1<<<(N + 7) / 8, 256, 0, stream>>>(agg1, h1s, dinv, b1, W2, h2s, N);
    k_edge_agg2<<<(E + 255) / 256, 256, 0, stream>>>(row, col, h2s, agg2, E);
    k_finish2<<<(N + 255) / 256, 256, 0, stream>>>(agg2, h2s, dinv, b2, out, N);
}

// Round 2
// 367.256 us; speedup vs baseline: 2.7901x; 2.7901x over previous
//
#include <hip/hip_runtime.h>
#include <hip/hip_bf16.h>
#include <math.h>

// GCN 2-layer: h1 = relu(Agg(x@W1)+b1); out = log_softmax(Agg(h1@W2)+b2)
// Agg factorized: out[i] = dinv[i] * ( sum_{e: col=i} hs[row_e] + hs[i] ) + b
// where hs[j] = dinv[j]*h[j]. Aggregation via CSR (counting sort by col),
// NO float scatter-atomics (R1: 51.2M atomics -> 800MB HBM write-through).

#define GNN_N 100000
#define GNN_E 1600000
#define NB 391   // ceil(N/256)

// ---- histogram of col ----
__global__ __launch_bounds__(256) void k_hist(const int* __restrict__ col,
                                              int* __restrict__ cnt, int e) {
    int i = blockIdx.x * 256 + threadIdx.x;
    if (i < e) atomicAdd(&cnt[col[i]], 1);
}

// dinv[i] = rsqrt(cnt[i]+1)  (in-degree incl self loop)
__global__ __launch_bounds__(256) void k_dinv(const int* __restrict__ cnt,
                                              float* __restrict__ dinv, int n) {
    int i = blockIdx.x * 256 + threadIdx.x;
    if (i < n) dinv[i] = rsqrtf((float)(cnt[i] + 1));
}

// ---- hierarchical exclusive scan of cnt -> offsets (and cursor copy) ----
__global__ __launch_bounds__(256) void k_scan1(const int* __restrict__ cnt,
                                               int* __restrict__ bsums, int n) {
    int i = blockIdx.x * 256 + threadIdx.x;
    int v = (i < n) ? cnt[i] : 0;
    #pragma unroll
    for (int m = 32; m >= 1; m >>= 1) v += __shfl_xor(v, m);
    __shared__ int ws[4];
    int lane = threadIdx.x & 63, wave = threadIdx.x >> 6;
    if (lane == 0) ws[wave] = v;
    __syncthreads();
    if (threadIdx.x == 0) bsums[blockIdx.x] = ws[0] + ws[1] + ws[2] + ws[3];
}

__global__ __launch_bounds__(512) void k_scan2(int* __restrict__ bsums, int nb) {
    // single block 512 threads: exclusive scan of bsums[0..nb)
    int tid = threadIdx.x;
    int v = (tid < nb) ? bsums[tid] : 0;
    int lane = tid & 63, wave = tid >> 6;
    int inc = v;
    #pragma unroll
    for (int d = 1; d < 64; d <<= 1) {
        int t = __shfl_up(inc, d);
        if (lane >= d) inc += t;
    }
    __shared__ int wsum[8];
    if (lane == 63) wsum[wave] = inc;
    __syncthreads();
    if (tid == 0) {
        int a = 0;
        #pragma unroll
        for (int w = 0; w < 8; ++w) { int t = wsum[w]; wsum[w] = a; a += t; }
    }
    __syncthreads();
    int ex = inc - v + wsum[wave];
    if (tid < nb) bsums[tid] = ex;
}

__global__ __launch_bounds__(256) void k_scan3(const int* __restrict__ cnt,
                                               const int* __restrict__ bsums,
                                               int* __restrict__ offsets,
                                               int* __restrict__ cursor, int n) {
    int i = blockIdx.x * 256 + threadIdx.x;
    int v = (i < n) ? cnt[i] : 0;
    int lane = threadIdx.x & 63, wave = threadIdx.x >> 6;
    int inc = v;
    #pragma unroll
    for (int d = 1; d < 64; d <<= 1) {
        int t = __shfl_up(inc, d);
        if (lane >= d) inc += t;
    }
    __shared__ int wsum[4];
    if (lane == 63) wsum[wave] = inc;
    __syncthreads();
    if (threadIdx.x == 0) {
        int a = 0;
        #pragma unroll
        for (int w = 0; w < 4; ++w) { int t = wsum[w]; wsum[w] = a; a += t; }
    }
    __syncthreads();
    int ex = inc - v + wsum[wave] + bsums[blockIdx.x];
    if (i < n) { offsets[i] = ex; cursor[i] = ex; }
}

// ---- scatter rows into CSR order ----
__global__ __launch_bounds__(256) void k_scatter(const int* __restrict__ row,
                                                 const int* __restrict__ col,
                                                 int* __restrict__ cursor,
                                                 int* __restrict__ sorted_row, int e) {
    int i = blockIdx.x * 256 + threadIdx.x;
    if (i >= e) return;
    int c = col[i];
    int pos = atomicAdd(&cursor[c], 1);
    sorted_row[pos] = row[i];
}

// ---- h1s[i,f] = dinv[i] * sum_k x[i,k]*W1[k,f] ----
#define MM1_NODES 64
__global__ __launch_bounds__(256) void k_matmul1(const float* __restrict__ x,
                                                 const float* __restrict__ W1,
                                                 const float* __restrict__ dinv,
                                                 float* __restrict__ h1s, int n) {
    __shared__ float xs[MM1_NODES * 129];
    __shared__ float w1s[128 * 32];
    const int tid = threadIdx.x;
    const int nodeBase = blockIdx.x * MM1_NODES;

    {
        const float4* w4 = (const float4*)W1;
        float4* s4 = (float4*)w1s;
        for (int i = tid; i < 1024; i += 256) s4[i] = w4[i];
    }
    {
        const float4* x4 = (const float4*)x;
        for (int i = tid; i < MM1_NODES * 32; i += 256) {
            int node = i >> 5;
            int k4 = i & 31;
            float4 v = make_float4(0.f, 0.f, 0.f, 0.f);
            if (nodeBase + node < n)
                v = x4[(size_t)(nodeBase + node) * 32 + k4];
            int b = node * 129 + k4 * 4;
            xs[b + 0] = v.x; xs[b + 1] = v.y; xs[b + 2] = v.z; xs[b + 3] = v.w;
        }
    }
    __syncthreads();

    const int fg = tid & 7;
    const int ng = tid >> 3;
    const int n0 = ng * 2;
    float4 acc0 = make_float4(0.f, 0.f, 0.f, 0.f);
    float4 acc1 = make_float4(0.f, 0.f, 0.f, 0.f);
    const float4* w1s4 = (const float4*)w1s;
    const float* xr0 = &xs[n0 * 129];
    const float* xr1 = &xs[(n0 + 1) * 129];
    #pragma unroll 8
    for (int k = 0; k < 128; ++k) {
        float4 w = w1s4[k * 8 + fg];
        float a = xr0[k];
        float b = xr1[k];
        acc0.x += a * w.x; acc0.y += a * w.y; acc0.z += a * w.z; acc0.w += a * w.w;
        acc1.x += b * w.x; acc1.y += b * w.y; acc1.z += b * w.z; acc1.w += b * w.w;
    }
    int gn0 = nodeBase + n0;
    if (gn0 < n) {
        float d = dinv[gn0];
        ((float4*)h1s)[(size_t)gn0 * 8 + fg] =
            make_float4(acc0.x * d, acc0.y * d, acc0.z * d, acc0.w * d);
    }
    if (gn0 + 1 < n) {
        float d = dinv[gn0 + 1];
        ((float4*)h1s)[(size_t)(gn0 + 1) * 8 + fg] =
            make_float4(acc1.x * d, acc1.y * d, acc1.z * d, acc1.w * d);
    }
}

// ---- layer1 gather + relu + b1 + (a1 @ W2) fused ----
// 8-thread team per node; lane j handles float4 feats [4j,4j+4)
__global__ __launch_bounds__(256) void k_gather1(const int* __restrict__ offsets,
                                                 const int* __restrict__ cnt,
                                                 const int* __restrict__ sorted_row,
                                                 const float* __restrict__ h1s,
                                                 const float* __restrict__ dinv,
                                                 const float* __restrict__ b1,
                                                 const float* __restrict__ W2,
                                                 float* __restrict__ h2s, int n) {
    int tid = threadIdx.x;
    int j = tid & 7;
    int team = tid >> 3;
    int node = blockIdx.x * 32 + team;
    if (node >= n) return;
    const float4* h4 = (const float4*)h1s;
    int start = offsets[node];
    int deg = cnt[node];
    float4 acc = h4[(size_t)node * 8 + j];   // self loop
    for (int k = 0; k < deg; ++k) {
        int r = sorted_row[start + k];
        float4 v = h4[(size_t)r * 8 + j];
        acc.x += v.x; acc.y += v.y; acc.z += v.z; acc.w += v.w;
    }
    float d = dinv[node];
    int f = j * 4;
    float a0 = fmaxf(d * acc.x + b1[f + 0], 0.f);
    float a1 = fmaxf(d * acc.y + b1[f + 1], 0.f);
    float a2 = fmaxf(d * acc.z + b1[f + 2], 0.f);
    float a3 = fmaxf(d * acc.w + b1[f + 3], 0.f);
    float s0 = a0 * W2[(f + 0) * 2] + a1 * W2[(f + 1) * 2] +
               a2 * W2[(f + 2) * 2] + a3 * W2[(f + 3) * 2];
    float s1 = a0 * W2[(f + 0) * 2 + 1] + a1 * W2[(f + 1) * 2 + 1] +
               a2 * W2[(f + 2) * 2 + 1] + a3 * W2[(f + 3) * 2 + 1];
    #pragma unroll
    for (int m = 4; m >= 1; m >>= 1) {
        s0 += __shfl_xor(s0, m);
        s1 += __shfl_xor(s1, m);
    }
    if (j == 0) ((float2*)h2s)[node] = make_float2(d * s0, d * s1);
}

// ---- layer2 gather + b2 + log_softmax fused ----
__global__ __launch_bounds__(256) void k_gather2(const int* __restrict__ offsets,
                                                 const int* __restrict__ cnt,
                                                 const int* __restrict__ sorted_row,
                                                 const float* __restrict__ h2s,
                                                 const float* __restrict__ dinv,
                                                 const float* __restrict__ b2,
                                                 float* __restrict__ out, int n) {
    int i = blockIdx.x * 256 + threadIdx.x;
    if (i >= n) return;
    const float2* h2 = (const float2*)h2s;
    int start = offsets[i];
    int deg = cnt[i];
    float2 acc = h2[i];   // self loop
    for (int k = 0; k < deg; ++k) {
        float2 v = h2[sorted_row[start + k]];
        acc.x += v.x; acc.y += v.y;
    }
    float d = dinv[i];
    float v0 = d * acc.x + b2[0];
    float v1 = d * acc.y + b2[1];
    float m = fmaxf(v0, v1);
    float l = m + logf(expf(v0 - m) + expf(v1 - m));
    ((float2*)out)[i] = make_float2(v0 - l, v1 - l);
}

extern "C" void kernel_launch(void* const* d_in, const int* in_sizes, int n_in,
                              void* d_out, int out_size, void* d_ws, size_t ws_size,
                              hipStream_t stream) {
    const float* x  = (const float*)d_in[0];
    const int*   ei = (const int*)d_in[1];   // [2,E] int32
    const float* W1 = (const float*)d_in[2];
    const float* b1 = (const float*)d_in[3];
    const float* W2 = (const float*)d_in[4];
    const float* b2 = (const float*)d_in[5];
    float* out = (float*)d_out;
    char* ws = (char*)d_ws;

    const int N = GNN_N, E = GNN_E;
    const int* row = ei;
    const int* col = ei + E;

    // workspace layout (4B units)
    float* dinv       = (float*)ws;                       // N
    float* h1s        = (float*)(ws + 4ull *   100000);   // N*32
    float* h2s        = (float*)(ws + 4ull *  3300000);   // N*2
    int*   cnt        = (int*)  (ws + 4ull *  3500000);   // N
    int*   offsets    = (int*)  (ws + 4ull *  3600000);   // N
    int*   cursor     = (int*)  (ws + 4ull *  3700000);   // N
    int*   bsums      = (int*)  (ws + 4ull *  3800000);   // 512
    int*   sorted_row = (int*)  (ws + 4ull *  3800576);   // E   (end: 5.4M*4B = 21.6MB)

    hipMemsetAsync(cnt, 0, (size_t)N * sizeof(int), stream);

    k_hist   <<<(E + 255) / 256, 256, 0, stream>>>(col, cnt, E);
    k_dinv   <<<NB, 256, 0, stream>>>(cnt, dinv, N);
    k_scan1  <<<NB, 256, 0, stream>>>(cnt, bsums, N);
    k_scan2  <<<1, 512, 0, stream>>>(bsums, NB);
    k_scan3  <<<NB, 256, 0, stream>>>(cnt, bsums, offsets, cursor, N);
    k_scatter<<<(E + 255) / 256, 256, 0, stream>>>(row, col, cursor, sorted_row, E);
    k_matmul1<<<(N + MM1_NODES - 1) / MM1_NODES, 256, 0, stream>>>(x, W1, dinv, h1s, N);
    k_gather1<<<(N + 31) / 32, 256, 0, stream>>>(offsets, cnt, sorted_row, h1s, dinv, b1, W2, h2s, N);
    k_gather2<<<NB, 256, 0, stream>>>(offsets, cnt, sorted_row, h2s, dinv, b2, out, N);
}

// Round 3
// 219.698 us; speedup vs baseline: 4.6640x; 1.6716x over previous
//
#include <hip/hip_runtime.h>
#include <hip/hip_bf16.h>
#include <math.h>
#include <stdint.h>

// GCN 2-layer: h1 = relu(Agg(x@W1)+b1); out = log_softmax(Agg(h1@W2)+b2)
// Agg factorized: out[i] = dinv[i] * ( sum_{e: col=i} hs[row_e] + hs[i] ) + b,
// hs[j] = dinv[j]*h[j].  CSR built by two-level LDS counting sort:
// R2 post-mortem: global cursor atomics = 105MB write-through, 130us. Now the
// only global atomics are 77K per-(block,bucket) reservations.

#define GNN_N 100000
#define GNN_E 1600000
#define NB 391        // ceil(N/256)
#define NBUCK 391     // coarse buckets: col>>8
#define CAP 4608      // slab capacity per bucket (mean 4096, sd 64 -> +8 sigma)
#define CH 8192       // edges per k_bucket block

// ---- pass 1: coarse bucket by col>>8, pack (row<<8)|(col&255) into slabs ----
__global__ __launch_bounds__(256) void k_bucket(const int* __restrict__ row,
                                                const int* __restrict__ col,
                                                int* __restrict__ bucket_fill,
                                                uint32_t* __restrict__ slab, int e) {
    __shared__ int hist[NBUCK];
    __shared__ int cur[NBUCK];
    __shared__ int base[NBUCK];
    const int tid = threadIdx.x;
    const int e0 = blockIdx.x * CH;
    const int m = min(CH, e - e0);

    for (int i = tid; i < NBUCK; i += 256) { hist[i] = 0; cur[i] = 0; }
    __syncthreads();
    for (int i = tid; i < m; i += 256)
        atomicAdd(&hist[col[e0 + i] >> 8], 1);
    __syncthreads();
    for (int i = tid; i < NBUCK; i += 256)
        base[i] = atomicAdd(&bucket_fill[i], hist[i]);
    __syncthreads();
    for (int i = tid; i < m; i += 256) {
        int c = col[e0 + i];
        int r = row[e0 + i];
        int b = c >> 8;
        int p = base[b] + atomicAdd(&cur[b], 1);
        if (p < CAP)   // statistically impossible overflow guard
            slab[(size_t)b * CAP + p] = ((uint32_t)r << 8) | (uint32_t)(c & 255);
    }
}

// ---- exclusive scan of bucket_fill[NBUCK] -> bucket_base ----
__global__ __launch_bounds__(512) void k_bucket_scan(const int* __restrict__ bucket_fill,
                                                     int* __restrict__ bucket_base, int nb) {
    int tid = threadIdx.x;
    int v = (tid < nb) ? bucket_fill[tid] : 0;
    int lane = tid & 63, wave = tid >> 6;
    int inc = v;
    #pragma unroll
    for (int d = 1; d < 64; d <<= 1) {
        int t = __shfl_up(inc, d);
        if (lane >= d) inc += t;
    }
    __shared__ int wsum[8];
    if (lane == 63) wsum[wave] = inc;
    __syncthreads();
    if (tid == 0) {
        int a = 0;
        #pragma unroll
        for (int w = 0; w < 8; ++w) { int t = wsum[w]; wsum[w] = a; a += t; }
    }
    __syncthreads();
    if (tid < nb) bucket_base[tid] = inc - v + wsum[wave];
}

// ---- pass 2: fine sort within bucket; emit sorted_row, cnt, offsets, dinv ----
__global__ __launch_bounds__(256) void k_fine(const uint32_t* __restrict__ slab,
                                              const int* __restrict__ bucket_fill,
                                              const int* __restrict__ bucket_base,
                                              int* __restrict__ sorted_row,
                                              int* __restrict__ cnt,
                                              int* __restrict__ offsets,
                                              float* __restrict__ dinv, int n) {
    __shared__ int hist[256];
    __shared__ int excl[256];
    __shared__ int cur[256];
    __shared__ int wsum[4];
    __shared__ uint32_t stage[CAP];
    const int tid = threadIdx.x;
    const int b = blockIdx.x;
    const int nb = min(bucket_fill[b], CAP);
    const int gbase = bucket_base[b];
    const uint32_t* sl = slab + (size_t)b * CAP;

    hist[tid] = 0; cur[tid] = 0;
    __syncthreads();
    for (int i = tid; i < nb; i += 256)
        atomicAdd(&hist[sl[i] & 255u], 1);
    __syncthreads();
    // exclusive scan of hist[256]
    {
        int v = hist[tid];
        int lane = tid & 63, wave = tid >> 6;
        int inc = v;
        #pragma unroll
        for (int d = 1; d < 64; d <<= 1) {
            int t = __shfl_up(inc, d);
            if (lane >= d) inc += t;
        }
        if (lane == 63) wsum[wave] = inc;
        __syncthreads();
        if (tid == 0) {
            int a = 0;
            #pragma unroll
            for (int w = 0; w < 4; ++w) { int t = wsum[w]; wsum[w] = a; a += t; }
        }
        __syncthreads();
        excl[tid] = inc - v + wsum[wave];
    }
    // per-col outputs
    {
        int c = b * 256 + tid;
        if (c < n) {
            int h = hist[tid];
            cnt[c] = h;
            offsets[c] = gbase + excl[tid];
            dinv[c] = rsqrtf((float)(h + 1));
        }
    }
    __syncthreads();
    // reorder into LDS stage by fine bin
    for (int i = tid; i < nb; i += 256) {
        uint32_t v = sl[i];
        int f = (int)(v & 255u);
        int p = atomicAdd(&cur[f], 1);
        stage[excl[f] + p] = v >> 8;
    }
    __syncthreads();
    // coalesced write of rows
    for (int i = tid; i < nb; i += 256)
        sorted_row[gbase + i] = (int)stage[i];
}

// ---- h1s[i,f] = dinv[i] * sum_k x[i,k]*W1[k,f] ----
#define MM1_NODES 64
__global__ __launch_bounds__(256) void k_matmul1(const float* __restrict__ x,
                                                 const float* __restrict__ W1,
                                                 const float* __restrict__ dinv,
                                                 float* __restrict__ h1s, int n) {
    __shared__ float xs[MM1_NODES * 129];
    __shared__ float w1s[128 * 32];
    const int tid = threadIdx.x;
    const int nodeBase = blockIdx.x * MM1_NODES;

    {
        const float4* w4 = (const float4*)W1;
        float4* s4 = (float4*)w1s;
        for (int i = tid; i < 1024; i += 256) s4[i] = w4[i];
    }
    {
        const float4* x4 = (const float4*)x;
        for (int i = tid; i < MM1_NODES * 32; i += 256) {
            int node = i >> 5;
            int k4 = i & 31;
            float4 v = make_float4(0.f, 0.f, 0.f, 0.f);
            if (nodeBase + node < n)
                v = x4[(size_t)(nodeBase + node) * 32 + k4];
            int bb = node * 129 + k4 * 4;
            xs[bb + 0] = v.x; xs[bb + 1] = v.y; xs[bb + 2] = v.z; xs[bb + 3] = v.w;
        }
    }
    __syncthreads();

    const int fg = tid & 7;
    const int ng = tid >> 3;
    const int n0 = ng * 2;
    float4 acc0 = make_float4(0.f, 0.f, 0.f, 0.f);
    float4 acc1 = make_float4(0.f, 0.f, 0.f, 0.f);
    const float4* w1s4 = (const float4*)w1s;
    const float* xr0 = &xs[n0 * 129];
    const float* xr1 = &xs[(n0 + 1) * 129];
    #pragma unroll 8
    for (int k = 0; k < 128; ++k) {
        float4 w = w1s4[k * 8 + fg];
        float a = xr0[k];
        float b = xr1[k];
        acc0.x += a * w.x; acc0.y += a * w.y; acc0.z += a * w.z; acc0.w += a * w.w;
        acc1.x += b * w.x; acc1.y += b * w.y; acc1.z += b * w.z; acc1.w += b * w.w;
    }
    int gn0 = nodeBase + n0;
    if (gn0 < n) {
        float d = dinv[gn0];
        ((float4*)h1s)[(size_t)gn0 * 8 + fg] =
            make_float4(acc0.x * d, acc0.y * d, acc0.z * d, acc0.w * d);
    }
    if (gn0 + 1 < n) {
        float d = dinv[gn0 + 1];
        ((float4*)h1s)[(size_t)(gn0 + 1) * 8 + fg] =
            make_float4(acc1.x * d, acc1.y * d, acc1.z * d, acc1.w * d);
    }
}

// ---- layer1 gather + relu + b1 + (a1 @ W2) fused ----
__global__ __launch_bounds__(256) void k_gather1(const int* __restrict__ offsets,
                                                 const int* __restrict__ cnt,
                                                 const int* __restrict__ sorted_row,
                                                 const float* __restrict__ h1s,
                                                 const float* __restrict__ dinv,
                                                 const float* __restrict__ b1,
                                                 const float* __restrict__ W2,
                                                 float* __restrict__ h2s, int n) {
    int tid = threadIdx.x;
    int j = tid & 7;
    int team = tid >> 3;
    int node = blockIdx.x * 32 + team;
    if (node >= n) return;
    const float4* h4 = (const float4*)h1s;
    int start = offsets[node];
    int deg = cnt[node];
    float4 acc = h4[(size_t)node * 8 + j];   // self loop
    for (int k = 0; k < deg; ++k) {
        int r = sorted_row[start + k];
        float4 v = h4[(size_t)r * 8 + j];
        acc.x += v.x; acc.y += v.y; acc.z += v.z; acc.w += v.w;
    }
    float d = dinv[node];
    int f = j * 4;
    float a0 = fmaxf(d * acc.x + b1[f + 0], 0.f);
    float a1 = fmaxf(d * acc.y + b1[f + 1], 0.f);
    float a2 = fmaxf(d * acc.z + b1[f + 2], 0.f);
    float a3 = fmaxf(d * acc.w + b1[f + 3], 0.f);
    float s0 = a0 * W2[(f + 0) * 2] + a1 * W2[(f + 1) * 2] +
               a2 * W2[(f + 2) * 2] + a3 * W2[(f + 3) * 2];
    float s1 = a0 * W2[(f + 0) * 2 + 1] + a1 * W2[(f + 1) * 2 + 1] +
               a2 * W2[(f + 2) * 2 + 1] + a3 * W2[(f + 3) * 2 + 1];
    #pragma unroll
    for (int m = 4; m >= 1; m >>= 1) {
        s0 += __shfl_xor(s0, m);
        s1 += __shfl_xor(s1, m);
    }
    if (j == 0) ((float2*)h2s)[node] = make_float2(d * s0, d * s1);
}

// ---- layer2 gather + b2 + log_softmax fused ----
__global__ __launch_bounds__(256) void k_gather2(const int* __restrict__ offsets,
                                                 const int* __restrict__ cnt,
                                                 const int* __restrict__ sorted_row,
                                                 const float* __restrict__ h2s,
                                                 const float* __restrict__ dinv,
                                                 const float* __restrict__ b2,
                                                 float* __restrict__ out, int n) {
    int i = blockIdx.x * 256 + threadIdx.x;
    if (i >= n) return;
    const float2* h2 = (const float2*)h2s;
    int start = offsets[i];
    int deg = cnt[i];
    float2 acc = h2[i];   // self loop
    for (int k = 0; k < deg; ++k) {
        float2 v = h2[sorted_row[start + k]];
        acc.x += v.x; acc.y += v.y;
    }
    float d = dinv[i];
    float v0 = d * acc.x + b2[0];
    float v1 = d * acc.y + b2[1];
    float m = fmaxf(v0, v1);
    float l = m + logf(expf(v0 - m) + expf(v1 - m));
    ((float2*)out)[i] = make_float2(v0 - l, v1 - l);
}

extern "C" void kernel_launch(void* const* d_in, const int* in_sizes, int n_in,
                              void* d_out, int out_size, void* d_ws, size_t ws_size,
                              hipStream_t stream) {
    const float* x  = (const float*)d_in[0];
    const int*   ei = (const int*)d_in[1];   // [2,E] int32
    const float* W1 = (const float*)d_in[2];
    const float* b1 = (const float*)d_in[3];
    const float* W2 = (const float*)d_in[4];
    const float* b2 = (const float*)d_in[5];
    float* out = (float*)d_out;
    char* ws = (char*)d_ws;

    const int N = GNN_N, E = GNN_E;
    const int* row = ei;
    const int* col = ei + E;

    // workspace layout (4B units); slab aliases h1s (slab dead before h1s written)
    float*    dinv        = (float*)   ws;                       // N
    int*      cnt         = (int*)    (ws + 4ull *  100000);     // N
    int*      offsets     = (int*)    (ws + 4ull *  200000);     // N
    int*      bucket_fill = (int*)    (ws + 4ull *  300000);     // 512
    int*      bucket_base = (int*)    (ws + 4ull *  300512);     // 512
    int*      sorted_row  = (int*)    (ws + 4ull *  301024);     // E
    float*    h2s         = (float*)  (ws + 4ull * 1901024);     // N*2
    float*    h1s         = (float*)  (ws + 4ull * 2101024);     // N*32 (12.8MB)
    uint32_t* slab        = (uint32_t*)(ws + 4ull * 2101024);    // NBUCK*CAP (7.2MB, aliased)
    // end: 5,301,024 * 4B = 21.2 MB

    hipMemsetAsync(bucket_fill, 0, NBUCK * sizeof(int), stream);

    k_bucket     <<<(E + CH - 1) / CH, 256, 0, stream>>>(row, col, bucket_fill, slab, E);
    k_bucket_scan<<<1, 512, 0, stream>>>(bucket_fill, bucket_base, NBUCK);
    k_fine       <<<NBUCK, 256, 0, stream>>>(slab, bucket_fill, bucket_base,
                                             sorted_row, cnt, offsets, dinv, N);
    k_matmul1    <<<(N + MM1_NODES - 1) / MM1_NODES, 256, 0, stream>>>(x, W1, dinv, h1s, N);
    k_gather1    <<<(N + 31) / 32, 256, 0, stream>>>(offsets, cnt, sorted_row, h1s, dinv, b1, W2, h2s, N);
    k_gather2    <<<NB, 256, 0, stream>>>(offsets, cnt, sorted_row, h2s, dinv, b2, out, N);
}

// Round 4
// 188.001 us; speedup vs baseline: 5.4503x; 1.1686x over previous
//
#include <hip/hip_runtime.h>
#include <hip/hip_bf16.h>
#include <math.h>
#include <stdint.h>

// GCN 2-layer: h1 = relu(Agg(x@W1)+b1); out = log_softmax(Agg(h1@W2)+b2)
// Agg factorized: out[i] = dinv[i] * ( sum_{e: col=i} hs[row_e] + hs[i] ) + b,
// hs[j] = dinv[j]*h[j].  CSR via two-level LDS counting sort.
// R3 post-mortem: k_bucket grid (196) < #CUs (256) -> 6.7% occupancy; gather1
// latency-bound on 128B fp32 rows. Now: CH=4096, regs-cached edges, bf16 h1s.

#define GNN_N 100000
#define GNN_E 1600000
#define NBUCK 391     // coarse buckets: col>>8
#define CAP 4608      // slab capacity per bucket (mean 4096, sd ~64)
#define CH 4096       // edges per k_bucket block (16/thread)

// ---- pass 1: coarse bucket by col>>8, pack (row<<8)|(col&255) into slabs ----
__global__ __launch_bounds__(256) void k_bucket(const int* __restrict__ row,
                                                const int* __restrict__ col,
                                                int* __restrict__ bucket_fill,
                                                uint32_t* __restrict__ slab, int e) {
    __shared__ int hist[NBUCK];
    __shared__ int base[NBUCK];
    const int tid = threadIdx.x;
    const int e0 = blockIdx.x * CH;
    const int m = min(CH, e - e0);
    const bool full = (m == CH);

    int cc[16], rr[16];
    for (int i = tid; i < NBUCK; i += 256) hist[i] = 0;
    __syncthreads();

    if (full) {
        #pragma unroll
        for (int t = 0; t < 16; ++t) {
            cc[t] = col[e0 + tid + t * 256];
            rr[t] = row[e0 + tid + t * 256];
        }
        #pragma unroll
        for (int t = 0; t < 16; ++t) atomicAdd(&hist[cc[t] >> 8], 1);
    } else {
        for (int i = tid; i < m; i += 256) atomicAdd(&hist[col[e0 + i] >> 8], 1);
    }
    __syncthreads();
    // rotated reservation: de-burst per-bin global atomic chains
    for (int i = tid; i < NBUCK; i += 256) {
        int bb = (i + blockIdx.x * 131) % NBUCK;
        base[bb] = atomicAdd(&bucket_fill[bb], hist[bb]);
    }
    __syncthreads();
    if (full) {
        #pragma unroll
        for (int t = 0; t < 16; ++t) {
            int b = cc[t] >> 8;
            int p = atomicAdd(&base[b], 1);
            if (p < CAP)
                slab[(size_t)b * CAP + p] = ((uint32_t)rr[t] << 8) | (uint32_t)(cc[t] & 255);
        }
    } else {
        for (int i = tid; i < m; i += 256) {
            int c = col[e0 + i];
            int r = row[e0 + i];
            int b = c >> 8;
            int p = atomicAdd(&base[b], 1);
            if (p < CAP)
                slab[(size_t)b * CAP + p] = ((uint32_t)r << 8) | (uint32_t)(c & 255);
        }
    }
}

// ---- exclusive scan of bucket_fill[NBUCK] -> bucket_base ----
__global__ __launch_bounds__(512) void k_bucket_scan(const int* __restrict__ bucket_fill,
                                                     int* __restrict__ bucket_base, int nb) {
    int tid = threadIdx.x;
    int v = (tid < nb) ? bucket_fill[tid] : 0;
    int lane = tid & 63, wave = tid >> 6;
    int inc = v;
    #pragma unroll
    for (int d = 1; d < 64; d <<= 1) {
        int t = __shfl_up(inc, d);
        if (lane >= d) inc += t;
    }
    __shared__ int wsum[8];
    if (lane == 63) wsum[wave] = inc;
    __syncthreads();
    if (tid == 0) {
        int a = 0;
        #pragma unroll
        for (int w = 0; w < 8; ++w) { int t = wsum[w]; wsum[w] = a; a += t; }
    }
    __syncthreads();
    if (tid < nb) bucket_base[tid] = inc - v + wsum[wave];
}

// ---- pass 2: fine sort within bucket; emit sorted_row, cnt, offsets, dinv ----
__global__ __launch_bounds__(512) void k_fine(const uint32_t* __restrict__ slab,
                                              const int* __restrict__ bucket_fill,
                                              const int* __restrict__ bucket_base,
                                              int* __restrict__ sorted_row,
                                              int* __restrict__ cnt,
                                              int* __restrict__ offsets,
                                              float* __restrict__ dinv, int n) {
    __shared__ int hist[256];
    __shared__ int excl[256];
    __shared__ int cur[256];
    __shared__ int wsum[4];
    __shared__ uint32_t stage[CAP];
    const int tid = threadIdx.x;
    const int b = blockIdx.x;
    const int nb = min(bucket_fill[b], CAP);
    const int gbase = bucket_base[b];
    const uint32_t* sl = slab + (size_t)b * CAP;

    if (tid < 256) { hist[tid] = 0; cur[tid] = 0; }
    __syncthreads();
    for (int i = tid; i < nb; i += 512)
        atomicAdd(&hist[sl[i] & 255u], 1);
    __syncthreads();
    int v = 0, inc = 0;
    const int lane = tid & 63, wave = tid >> 6;
    if (tid < 256) {
        v = hist[tid];
        inc = v;
        #pragma unroll
        for (int d = 1; d < 64; d <<= 1) {
            int t = __shfl_up(inc, d);
            if (lane >= d) inc += t;
        }
        if (lane == 63) wsum[wave] = inc;
    }
    __syncthreads();
    if (tid == 0) {
        int a = 0;
        #pragma unroll
        for (int w = 0; w < 4; ++w) { int t = wsum[w]; wsum[w] = a; a += t; }
    }
    __syncthreads();
    if (tid < 256) {
        int ex = inc - v + wsum[wave];
        excl[tid] = ex;
        int c = b * 256 + tid;
        if (c < n) {
            cnt[c] = v;
            offsets[c] = gbase + ex;
            dinv[c] = rsqrtf((float)(v + 1));
        }
    }
    __syncthreads();
    for (int i = tid; i < nb; i += 512) {
        uint32_t u = sl[i];
        int f = (int)(u & 255u);
        int p = atomicAdd(&cur[f], 1);
        stage[excl[f] + p] = u >> 8;
    }
    __syncthreads();
    for (int i = tid; i < nb; i += 512)
        sorted_row[gbase + i] = (int)stage[i];
}

// ---- bf16 helpers ----
__device__ inline uint32_t pack_bf16(float a, float b) {
    uint32_t ua = __float_as_uint(a);
    uint32_t ub = __float_as_uint(b);
    ua = (ua + 0x7fffu + ((ua >> 16) & 1u)) >> 16;
    ub = (ub + 0x7fffu + ((ub >> 16) & 1u)) >> 16;
    return ua | (ub << 16);
}
__device__ inline void bf8_acc(float* acc, uint4 u) {
    acc[0] += __uint_as_float(u.x << 16);
    acc[1] += __uint_as_float(u.x & 0xffff0000u);
    acc[2] += __uint_as_float(u.y << 16);
    acc[3] += __uint_as_float(u.y & 0xffff0000u);
    acc[4] += __uint_as_float(u.z << 16);
    acc[5] += __uint_as_float(u.z & 0xffff0000u);
    acc[6] += __uint_as_float(u.w << 16);
    acc[7] += __uint_as_float(u.w & 0xffff0000u);
}

// ---- h1s[i,f] = bf16( dinv[i] * sum_k x[i,k]*W1[k,f] ) ----
#define MM1_NODES 64
__global__ __launch_bounds__(256) void k_matmul1(const float* __restrict__ x,
                                                 const float* __restrict__ W1,
                                                 const float* __restrict__ dinv,
                                                 uint32_t* __restrict__ h1s, int n) {
    __shared__ float xs[MM1_NODES * 129];
    __shared__ float w1s[128 * 32];
    const int tid = threadIdx.x;
    const int nodeBase = blockIdx.x * MM1_NODES;

    {
        const float4* w4 = (const float4*)W1;
        float4* s4 = (float4*)w1s;
        for (int i = tid; i < 1024; i += 256) s4[i] = w4[i];
    }
    {
        const float4* x4 = (const float4*)x;
        for (int i = tid; i < MM1_NODES * 32; i += 256) {
            int node = i >> 5;
            int k4 = i & 31;
            float4 v = make_float4(0.f, 0.f, 0.f, 0.f);
            if (nodeBase + node < n)
                v = x4[(size_t)(nodeBase + node) * 32 + k4];
            int bb = node * 129 + k4 * 4;
            xs[bb + 0] = v.x; xs[bb + 1] = v.y; xs[bb + 2] = v.z; xs[bb + 3] = v.w;
        }
    }
    __syncthreads();

    const int fg = tid & 7;
    const int ng = tid >> 3;
    const int n0 = ng * 2;
    float4 acc0 = make_float4(0.f, 0.f, 0.f, 0.f);
    float4 acc1 = make_float4(0.f, 0.f, 0.f, 0.f);
    const float4* w1s4 = (const float4*)w1s;
    const float* xr0 = &xs[n0 * 129];
    const float* xr1 = &xs[(n0 + 1) * 129];
    #pragma unroll 8
    for (int k = 0; k < 128; ++k) {
        float4 w = w1s4[k * 8 + fg];
        float a = xr0[k];
        float b = xr1[k];
        acc0.x += a * w.x; acc0.y += a * w.y; acc0.z += a * w.z; acc0.w += a * w.w;
        acc1.x += b * w.x; acc1.y += b * w.y; acc1.z += b * w.z; acc1.w += b * w.w;
    }
    int gn0 = nodeBase + n0;
    if (gn0 < n) {
        float d = dinv[gn0];
        uint2 o = make_uint2(pack_bf16(acc0.x * d, acc0.y * d),
                             pack_bf16(acc0.z * d, acc0.w * d));
        ((uint2*)h1s)[(size_t)gn0 * 8 + fg] = o;
    }
    if (gn0 + 1 < n) {
        float d = dinv[gn0 + 1];
        uint2 o = make_uint2(pack_bf16(acc1.x * d, acc1.y * d),
                             pack_bf16(acc1.z * d, acc1.w * d));
        ((uint2*)h1s)[(size_t)(gn0 + 1) * 8 + fg] = o;
    }
}

// ---- layer1 gather (bf16 rows) + relu + b1 + (a1 @ W2) fused ----
// 4-lane team per node; lane l handles feats 8l..8l+7 (one 16B load)
__global__ __launch_bounds__(256) void k_gather1(const int* __restrict__ offsets,
                                                 const int* __restrict__ cnt,
                                                 const int* __restrict__ sorted_row,
                                                 const uint32_t* __restrict__ h1s,
                                                 const float* __restrict__ dinv,
                                                 const float* __restrict__ b1,
                                                 const float* __restrict__ W2,
                                                 float* __restrict__ h2s, int n) {
    const int tid = threadIdx.x;
    const int l = tid & 3;
    const int node = blockIdx.x * 64 + (tid >> 2);
    if (node >= n) return;
    const uint4* h4 = (const uint4*)h1s;   // 4 uint4 per 32-feat row
    float acc[8], acc2[8];
    #pragma unroll
    for (int j = 0; j < 8; ++j) { acc[j] = 0.f; acc2[j] = 0.f; }
    bf8_acc(acc, h4[(size_t)node * 4 + l]);   // self loop
    const int start = offsets[node];
    const int deg = cnt[node];
    int k = 0;
    for (; k + 2 <= deg; k += 2) {
        int r0 = sorted_row[start + k];
        int r1 = sorted_row[start + k + 1];
        uint4 ua = h4[(size_t)r0 * 4 + l];
        uint4 ub = h4[(size_t)r1 * 4 + l];
        bf8_acc(acc, ua);
        bf8_acc(acc2, ub);
    }
    if (k < deg) {
        int r = sorted_row[start + k];
        bf8_acc(acc, h4[(size_t)r * 4 + l]);
    }
    #pragma unroll
    for (int j = 0; j < 8; ++j) acc[j] += acc2[j];

    const float d = dinv[node];
    const int f0 = l * 8;
    float s0 = 0.f, s1 = 0.f;
    #pragma unroll
    for (int j = 0; j < 8; ++j) {
        float a = fmaxf(d * acc[j] + b1[f0 + j], 0.f);
        s0 += a * W2[(f0 + j) * 2];
        s1 += a * W2[(f0 + j) * 2 + 1];
    }
    s0 += __shfl_xor(s0, 1); s0 += __shfl_xor(s0, 2);
    s1 += __shfl_xor(s1, 1); s1 += __shfl_xor(s1, 2);
    if (l == 0) ((float2*)h2s)[node] = make_float2(d * s0, d * s1);
}

// ---- layer2 gather + b2 + log_softmax; edges split across 4 lanes ----
__global__ __launch_bounds__(256) void k_gather2(const int* __restrict__ offsets,
                                                 const int* __restrict__ cnt,
                                                 const int* __restrict__ sorted_row,
                                                 const float* __restrict__ h2s,
                                                 const float* __restrict__ dinv,
                                                 const float* __restrict__ b2,
                                                 float* __restrict__ out, int n) {
    const int tid = threadIdx.x;
    const int l = tid & 3;
    const int node = blockIdx.x * 64 + (tid >> 2);
    if (node >= n) return;
    const float2* h2 = (const float2*)h2s;
    float sx = 0.f, sy = 0.f;
    if (l == 0) { float2 s = h2[node]; sx = s.x; sy = s.y; }   // self loop
    const int start = offsets[node];
    const int deg = cnt[node];
    for (int k = l; k < deg; k += 4) {
        float2 v = h2[sorted_row[start + k]];
        sx += v.x; sy += v.y;
    }
    sx += __shfl_xor(sx, 1); sx += __shfl_xor(sx, 2);
    sy += __shfl_xor(sy, 1); sy += __shfl_xor(sy, 2);
    if (l == 0) {
        float d = dinv[node];
        float v0 = d * sx + b2[0];
        float v1 = d * sy + b2[1];
        float m = fmaxf(v0, v1);
        float lg = m + logf(expf(v0 - m) + expf(v1 - m));
        ((float2*)out)[node] = make_float2(v0 - lg, v1 - lg);
    }
}

extern "C" void kernel_launch(void* const* d_in, const int* in_sizes, int n_in,
                              void* d_out, int out_size, void* d_ws, size_t ws_size,
                              hipStream_t stream) {
    const float* x  = (const float*)d_in[0];
    const int*   ei = (const int*)d_in[1];   // [2,E] int32
    const float* W1 = (const float*)d_in[2];
    const float* b1 = (const float*)d_in[3];
    const float* W2 = (const float*)d_in[4];
    const float* b2 = (const float*)d_in[5];
    float* out = (float*)d_out;
    char* ws = (char*)d_ws;

    const int N = GNN_N, E = GNN_E;
    const int* row = ei;
    const int* col = ei + E;

    // workspace layout (4B words), no aliasing
    float*    dinv        = (float*)    ws;                       // N
    int*      cnt         = (int*)     (ws + 4ull *  100000);     // N
    int*      offsets     = (int*)     (ws + 4ull *  200000);     // N
    int*      bucket_fill = (int*)     (ws + 4ull *  300000);     // 512
    int*      bucket_base = (int*)     (ws + 4ull *  300512);     // 512
    int*      sorted_row  = (int*)     (ws + 4ull *  301024);     // E
    float*    h2s         = (float*)   (ws + 4ull * 1901024);     // N*2
    uint32_t* h1s         = (uint32_t*)(ws + 4ull * 2101024);     // N*16 (bf16 x32)
    uint32_t* slab        = (uint32_t*)(ws + 4ull * 3701024);     // NBUCK*CAP
    // end: 5,502,752 words = 22 MB

    hipMemsetAsync(bucket_fill, 0, NBUCK * sizeof(int), stream);

    k_bucket     <<<(E + CH - 1) / CH, 256, 0, stream>>>(row, col, bucket_fill, slab, E);
    k_bucket_scan<<<1, 512, 0, stream>>>(bucket_fill, bucket_base, NBUCK);
    k_fine       <<<NBUCK, 512, 0, stream>>>(slab, bucket_fill, bucket_base,
                                             sorted_row, cnt, offsets, dinv, N);
    k_matmul1    <<<(N + MM1_NODES - 1) / MM1_NODES, 256, 0, stream>>>(x, W1, dinv, h1s, N);
    k_gather1    <<<(N + 63) / 64, 256, 0, stream>>>(offsets, cnt, sorted_row, h1s, dinv, b1, W2, h2s, N);
    k_gather2    <<<(N + 63) / 64, 256, 0, stream>>>(offsets, cnt, sorted_row, h2s, dinv, b2, out, N);
}